// Round 10
// baseline (233.218 us; speedup 1.0000x reference)
//
#include <hip/hip_runtime.h>
#include <hip/hip_fp16.h>

#define B_ 16
#define C_ 3
#define H_ 384
#define W_ 1280
#define HW_ (H_*W_)
#define EPS_ 1e-7f

// LEDGER: R0-R5 pinned ~110us -> scattered lane-request rate (TA/TCP) is the
// bottleneck. R7: RGBX-fp16 repack, 2 scatter/px -> 67.5us. R8: coalesced
// VMEM 12->8 per 2px -> 59us. R9: VALU -14pts, VGPR 28->20, dur UNCHANGED ->
// scatter pipe pins warp2; VALU/addressing free. R10 (this): (a) 4px/thread:
// depth+stores become dwordx4 -> 12 VMEM/4px (was 16), 8 scattered gathers
// in flight (2x MLP); (b) pad pass fused into repack (one fewer launch).
#define WP_ 1284                        // 2 left + 1280 + 2 right
#define HP_ 386                         // 1 top + 384 + 1 bottom
#define NXCD_ 8

// warp2 v4 tiling: 256 cols x 4 rows per block, 4px/thread along x.
#define COLS_ 256
#define BANDS_ (W_/COLS_)               // 5
#define RTILES_ (H_/4)                  // 96
#define NBLK4_ (BANDS_*RTILES_*B_)      // 7680 (div 8 -> swizzle bijective)
#define CPX4_  (NBLK4_/NXCD_)           // 960

// pad cells per batch: top row + bottom row + 4 side cells per interior row
#define PADPB_ (2*WP_ + 4*H_)           // 4104
#define NPAD_  (B_*PADPB_)              // 65664

typedef float v2f __attribute__((ext_vector_type(2)));
typedef float v4f __attribute__((ext_vector_type(4)));

__device__ __forceinline__ v2f load2(const float* p) {
  v2f r; __builtin_memcpy(&r, p, 8); return r;
}
__device__ __forceinline__ uint4 load16u(const void* p) {
  uint4 r; __builtin_memcpy(&r, p, 16); return r;
}
__device__ __forceinline__ v4f ntload4(const float* p) {
  return __builtin_nontemporal_load((const v4f*)p);   // 16B-aligned
}
__device__ __forceinline__ unsigned pack2(float a, float b) {
  __half2 h = __floats2half2_rn(a, b);
  unsigned u; __builtin_memcpy(&u, &h, 4); return u;
}

__device__ __forceinline__ void mat3mul(const float* A, const float* Bm, float* C) {
  #pragma unroll
  for (int i = 0; i < 3; i++)
    #pragma unroll
    for (int j = 0; j < 3; j++)
      C[i*3+j] = A[i*3+0]*Bm[0*3+j] + A[i*3+1]*Bm[1*3+j] + A[i*3+2]*Bm[2*3+j];
}

// M = K * R * inv(K), T = K * t for batch b.
__device__ void compute_MT(const float* __restrict__ pose,
                           const float* __restrict__ intr,
                           int b, float* M, float* T)
{
  float K[9];
  #pragma unroll
  for (int i = 0; i < 9; i++) K[i] = intr[b*9 + i];
  float aa0 = pose[b*6 + 0], aa1 = pose[b*6 + 1], aa2 = pose[b*6 + 2];
  float t0  = pose[b*6 + 3], t1  = pose[b*6 + 4], t2  = pose[b*6 + 5];

  float theta = sqrtf(aa0*aa0 + aa1*aa1 + aa2*aa2);
  float invn  = 1.0f / (theta + EPS_);
  float x = aa0*invn, y = aa1*invn, z = aa2*invn;
  float c = cosf(theta), s = sinf(theta), t = 1.0f - c;
  float R[9] = {
    t*x*x + c,   t*x*y - s*z, t*z*x + s*y,
    t*x*y + s*z, t*y*y + c,   t*y*z - s*x,
    t*z*x - s*y, t*y*z + s*x, t*z*z + c
  };

  float a = K[0], bb = K[1], cc = K[2];
  float d = K[3], e  = K[4], f  = K[5];
  float g = K[6], h  = K[7], ii = K[8];
  float A0 = e*ii - f*h, A1 = f*g - d*ii, A2 = d*h - e*g;
  float id = 1.0f / (a*A0 + bb*A1 + cc*A2);
  float iK[9] = {
    A0*id, (cc*h - bb*ii)*id, (bb*f - cc*e)*id,
    A1*id, (a*ii - cc*g)*id,  (cc*d - a*f)*id,
    A2*id, (bb*g - a*h)*id,   (a*e  - bb*d)*id
  };

  float KR[9];
  mat3mul(K, R, KR);
  mat3mul(KR, iK, M);
  T[0] = K[0]*t0 + K[1]*t1 + K[2]*t2;
  T[1] = K[3]*t0 + K[4]*t1 + K[5]*t2;
  T[2] = K[6]*t0 + K[7]*t1 + K[8]*t2;
}

// ---- Pass 1 (fused): planar f32 -> PADDED interleaved RGBX fp16 (8B/px),
// 4px/thread; first NPAD_ threads ALSO zero one border cell (disjoint from
// data cells -> no ordering hazard; saves the separate pad dispatch).
__global__ __launch_bounds__(256) void repack_kernel(
    const float* __restrict__ src, uint4* __restrict__ ws)
{
  int tg = blockIdx.x * 256 + threadIdx.x;     // quad index, exact fit

  if (tg < NPAD_) {
    int pb = tg / PADPB_;
    int k  = tg - pb * PADPB_;
    int row, col;
    if (k < WP_)            { row = 0;       col = k; }
    else if (k < 2*WP_)     { row = HP_ - 1; col = k - WP_; }
    else {
      int kk = k - 2*WP_;
      row = (kk >> 2) + 1;
      int c4 = kk & 3;
      col = (c4 < 2) ? c4 : (WP_ - 4 + c4);   // {0,1,1282,1283}
    }
    ((unsigned long long*)ws)[(size_t)(pb * HP_ + row) * WP_ + col] = 0ULL;
  }

  int b  = tg / (HW_/4);
  int rq = tg - b * (HW_/4);
  int p  = rq * 4;
  int y  = p / W_;
  int x  = p - y * W_;
  const float* s = src + (size_t)b * 3 * HW_ + p;
  v4f c0 = ntload4(s);                 // nt: src is dead after this pass
  v4f c1 = ntload4(s + HW_);
  v4f c2 = ntload4(s + 2*HW_);
  uint4 o0, o1;
  o0.x = pack2(c0.x, c1.x); o0.y = pack2(c2.x, 0.0f);   // px0
  o0.z = pack2(c0.y, c1.y); o0.w = pack2(c2.y, 0.0f);   // px1
  o1.x = pack2(c0.z, c1.z); o1.y = pack2(c2.z, 0.0f);   // px2
  o1.z = pack2(c0.w, c1.w); o1.w = pack2(c2.w, 0.0f);   // px3
  // slot of pixel (y,x): (b*HP + y+1)*WP + (x+2); x%4==0 -> slot even
  size_t slot = (size_t)(b * HP_ + y + 1) * WP_ + (x + 2);
  ws[slot >> 1]       = o0;            // regular stores: must stay cached
  ws[(slot >> 1) + 1] = o1;
}

// ---- Pass 2 v4: 4 px/thread, 256x4 tile, XCD swizzle, padded layout.
// Per 4px: 8 scattered dwordx4 (structural floor, all in flight) +
// 1 dwordx4 depth + 3 dwordx4 stores = 12 VMEM (R8/R9 was 16).
__global__ __launch_bounds__(256) void warp2_kernel(
    const uint4* __restrict__ pk,
    const float* __restrict__ depth,
    const float* __restrict__ pose,
    const float* __restrict__ intr,
    float* __restrict__ out)
{
  __shared__ float sp[12];

  // XCD-aware bijective swizzle, row-tile fastest within each XCD chunk.
  int l = blockIdx.x;
  int w = (l & (NXCD_-1)) * CPX4_ + (l >> 3);
  int rt   = w % RTILES_;
  int tmp  = w / RTILES_;
  int band = tmp % BANDS_;
  int b    = tmp / BANDS_;

  int t  = threadIdx.x;
  int rr = t >> 6;                  // row 0..3 within the 4-row tile
  int j0 = band * COLS_ + (t & 63) * 4;
  int i  = rt * 4 + rr;

  // Coalesced dwordx4 depth load before the barrier (hides under M/T).
  v4f dq = *(const v4f*)(depth + (size_t)b * HW_ + (size_t)i * W_ + j0);

  if (t == 0) {
    float M[9], T[3];
    compute_MT(pose, intr, b, M, T);
    #pragma unroll
    for (int k = 0; k < 9; k++) sp[k] = M[k];
    #pragma unroll
    for (int k = 0; k < 3; k++) sp[9 + k] = T[k];
  }
  __syncthreads();
  float m00 = sp[0], m01 = sp[1], m02 = sp[2];
  float m10 = sp[3], m11 = sp[4], m12 = sp[5];
  float m20 = sp[6], m21 = sp[7], m22 = sp[8];
  float T0  = sp[9], T1  = sp[10], T2 = sp[11];

  float yf = (float)i;
  float bx = m01*yf + m02;
  float by = m11*yf + m12;
  float bz = m21*yf + m22;

  const char* pkb = (const char*)pk;
  const float Wm1 = (float)(W_-1), Hm1 = (float)(H_-1);
  int rowbase = b * HP_;

  // Per-pixel projection -> masked tap weights + byte offset (R9 lean math:
  // padded layout => slots == taps, no merge network; rcp for the divide).
  float w00[4], w01[4], w10[4], w11[4];
  size_t off0[4];
  #pragma unroll
  for (int q = 0; q < 4; q++) {
    float xf = (float)(j0 + q);
    float d  = dq[q];
    float cz = (m20*xf + bz)*d + T2;
    float iv = __builtin_amdgcn_rcpf(cz + EPS_);
    float px = ((m00*xf + bx)*d + T0) * iv;
    float py = ((m10*xf + by)*d + T1) * iv;
    float x0 = floorf(px), y0 = floorf(py);
    float fx1 = px - x0, fx0 = 1.0f - fx1;
    float fy1 = py - y0, fy0 = 1.0f - fy1;
    float wx0 = (x0 >= 0.0f      && x0 <= Wm1) ? fx0 : 0.0f;
    float wx1 = (x0+1.0f >= 0.0f && x0+1.0f <= Wm1) ? fx1 : 0.0f;
    float wy0 = (y0 >= 0.0f      && y0 <= Hm1) ? fy0 : 0.0f;
    float wy1 = (y0+1.0f >= 0.0f && y0+1.0f <= Hm1) ? fy1 : 0.0f;
    w00[q] = wx0*wy0; w01[q] = wx1*wy0; w10[q] = wx0*wy1; w11[q] = wx1*wy1;
    int xb = (int)fminf(fmaxf(x0, -1.0f), Wm1);
    int yb = (int)fminf(fmaxf(y0, -1.0f), Hm1);
    off0[q] = ((size_t)(rowbase + yb + 1) * WP_ + (xb + 2)) * 8;
  }

  // ---- 8 scattered gathers back-to-back (row1 = row0 + stride bytes).
  uint4 R0[4], R1[4];
  #pragma unroll
  for (int q = 0; q < 4; q++) {
    R0[q] = load16u(pkb + off0[q]);
    R1[q] = load16u(pkb + off0[q] + (size_t)WP_*8);
  }
  // Fence: all 8 issue before the first consumer (R2/R3 lesson: source
  // order alone lets the compiler serialize into register-reuse batches).
  __builtin_amdgcn_sched_barrier(0);

  v4f o0, o1, o2;
  #pragma unroll
  for (int q = 0; q < 4; q++) {
    // dwords = [slot0:{c0,c1},{c2,pad} | slot1:{c0,c1},{c2,pad}]
    float2 A00 = __half22float2(*(const __half2*)&R0[q].x);
    float  A02 = __low2float  (*(const __half2*)&R0[q].y);
    float2 A01 = __half22float2(*(const __half2*)&R0[q].z);
    float  A03 = __low2float  (*(const __half2*)&R0[q].w);
    float2 A10 = __half22float2(*(const __half2*)&R1[q].x);
    float  A12 = __low2float  (*(const __half2*)&R1[q].y);
    float2 A11 = __half22float2(*(const __half2*)&R1[q].z);
    float  A13 = __low2float  (*(const __half2*)&R1[q].w);
    o0[q] = A00.x*w00[q] + A01.x*w01[q] + A10.x*w10[q] + A11.x*w11[q];
    o1[q] = A00.y*w00[q] + A01.y*w01[q] + A10.y*w10[q] + A11.y*w11[q];
    o2[q] = A02  *w00[q] + A03  *w01[q] + A12  *w10[q] + A13  *w11[q];
  }

  // 3 coalesced dwordx4 nt-stores (j0 % 4 == 0 -> 16B-aligned).
  size_t sb = (size_t)b * C_ * HW_;
  size_t op = (size_t)i * W_ + j0;
  __builtin_nontemporal_store(o0, (v4f*)(out + sb + op));
  __builtin_nontemporal_store(o1, (v4f*)(out + sb + HW_ + op));
  __builtin_nontemporal_store(o2, (v4f*)(out + sb + 2*(size_t)HW_ + op));
}

// ---- Fallback (ws too small): the proven R0 baseline (108.9us). ----
__global__ __launch_bounds__(256) void warp_fb_kernel(
    const float* __restrict__ src,
    const float* __restrict__ depth,
    const float* __restrict__ pose,
    const float* __restrict__ intr,
    float* __restrict__ out)
{
  __shared__ float sp[12];
  int b = blockIdx.y;
  if (threadIdx.x == 0) {
    float M[9], T[3];
    compute_MT(pose, intr, b, M, T);
    #pragma unroll
    for (int k = 0; k < 9; k++) sp[k] = M[k];
    #pragma unroll
    for (int k = 0; k < 3; k++) sp[9 + k] = T[k];
  }
  __syncthreads();
  float m00 = sp[0], m01 = sp[1], m02 = sp[2];
  float m10 = sp[3], m11 = sp[4], m12 = sp[5];
  float m20 = sp[6], m21 = sp[7], m22 = sp[8];
  float T0  = sp[9], T1  = sp[10], T2 = sp[11];

  int p = blockIdx.x * 256 + threadIdx.x;
  int j = p % W_;
  int i = p / W_;

  float d  = depth[(size_t)b * HW_ + p];
  float xf = (float)j, yf = (float)i;
  float cx = (m00*xf + m01*yf + m02)*d + T0;
  float cy = (m10*xf + m11*yf + m12)*d + T1;
  float cz = (m20*xf + m21*yf + m22)*d + T2;
  float inv = 1.0f / (cz + EPS_);
  float px = cx * inv, py = cy * inv;

  float x0f = floorf(px), y0f = floorf(py);
  float x1f = x0f + 1.0f, y1f = y0f + 1.0f;
  float wx1 = px - x0f, wx0 = 1.0f - wx1;
  float wy1 = py - y0f, wy0 = 1.0f - wy1;
  float mx0 = (x0f >= 0.0f && x0f <= (float)(W_-1)) ? 1.0f : 0.0f;
  float mx1 = (x1f >= 0.0f && x1f <= (float)(W_-1)) ? 1.0f : 0.0f;
  float my0 = (y0f >= 0.0f && y0f <= (float)(H_-1)) ? 1.0f : 0.0f;
  float my1 = (y1f >= 0.0f && y1f <= (float)(H_-1)) ? 1.0f : 0.0f;
  int xc0 = (int)fminf(fmaxf(x0f, 0.0f), (float)(W_-1));
  int xc1 = (int)fminf(fmaxf(x1f, 0.0f), (float)(W_-1));
  int yc0 = (int)fminf(fmaxf(y0f, 0.0f), (float)(H_-1));
  int yc1 = (int)fminf(fmaxf(y1f, 0.0f), (float)(H_-1));
  float w00 = wx0*wy0*mx0*my0;
  float w01 = wx1*wy0*mx1*my0;
  float w10 = wx0*wy1*mx0*my1;
  float w11 = wx1*wy1*mx1*my1;
  int base = xc0 < (W_-2) ? xc0 : (W_-2);
  bool s0 = (xc0 == base);
  bool s1 = (xc1 == base + 1);
  float wax = (s0 ? w00 : 0.0f) + (s1 ? 0.0f : w01);
  float way = (s0 ? 0.0f : w00) + (s1 ? w01 : 0.0f);
  float wbx = (s0 ? w10 : 0.0f) + (s1 ? 0.0f : w11);
  float wby = (s0 ? 0.0f : w10) + (s1 ? w11 : 0.0f);
  int rb0 = yc0*W_ + base;
  int rb1 = yc1*W_ + base;

  size_t sb = (size_t)b * C_ * HW_;
  const float* s0p = src + sb;
  const float* s1p = s0p + HW_;
  const float* s2p = s1p + HW_;
  v2f a0 = load2(s0p + rb0);
  v2f b0 = load2(s0p + rb1);
  v2f a1 = load2(s1p + rb0);
  v2f b1 = load2(s1p + rb1);
  v2f a2 = load2(s2p + rb0);
  v2f b2 = load2(s2p + rb1);
  float v0 = a0.x*wax + a0.y*way + b0.x*wbx + b0.y*wby;
  float v1 = a1.x*wax + a1.y*way + b1.x*wbx + b1.y*wby;
  float v2 = a2.x*wax + a2.y*way + b2.x*wbx + b2.y*wby;
  size_t op = (size_t)p;
  __builtin_nontemporal_store(v0, &out[sb + op]);
  __builtin_nontemporal_store(v1, &out[sb + HW_ + op]);
  __builtin_nontemporal_store(v2, &out[sb + 2*(size_t)HW_ + op]);
}

extern "C" void kernel_launch(void* const* d_in, const int* in_sizes, int n_in,
                              void* d_out, int out_size, void* d_ws, size_t ws_size,
                              hipStream_t stream) {
  const float* src   = (const float*)d_in[0];
  const float* depth = (const float*)d_in[1];
  const float* pose  = (const float*)d_in[2];
  const float* intr  = (const float*)d_in[3];
  float* out = (float*)d_out;

  const size_t need = (size_t)B_ * HP_ * WP_ * 8;   // 63.4 MB padded RGBX-fp16
  if (d_ws != nullptr && ws_size >= need) {
    repack_kernel<<<dim3(B_*HW_/4/256), 256, 0, stream>>>(src, (uint4*)d_ws);
    warp2_kernel<<<dim3(NBLK4_), 256, 0, stream>>>((const uint4*)d_ws, depth, pose, intr, out);
  } else {
    dim3 grid(HW_ / 256, B_);
    warp_fb_kernel<<<grid, 256, 0, stream>>>(src, depth, pose, intr, out);
  }
}